// Round 4
// baseline (888.513 us; speedup 1.0000x reference)
//
#include <hip/hip_runtime.h>
#include <hip/hip_bf16.h>

#define B_  512
#define S_  196
#define D_  1024
#define A_  512
#define O_  1000

typedef __attribute__((ext_vector_type(8))) __bf16 bf16x8_t;
typedef __attribute__((ext_vector_type(16))) float f32x16;
typedef __attribute__((ext_vector_type(4))) float f32x4v;

__device__ __forceinline__ unsigned short f2bf(float f) {
    union { float f; unsigned u; } v; v.f = f;
    unsigned r = v.u + 0x7FFFu + ((v.u >> 16) & 1u);   // RNE
    return (unsigned short)(r >> 16);
}

__device__ __forceinline__ unsigned pk2(float lo, float hi) {
    return (unsigned)f2bf(lo) | ((unsigned)f2bf(hi) << 16);
}

// ---- pack Wi [D][A] f32 -> Bp fragment-linear bf16: [nfrag(16)][kk(64)][lane(64)][8]
__global__ void bpack(const float* __restrict__ Wi, unsigned short* __restrict__ Bp) {
    int n = blockIdx.x, ks = blockIdx.y, l = threadIdx.x;
    int a  = n * 32 + (l & 31);
    int kb = ks * 16 + (l >> 5) * 8;
    unsigned short o[8];
    #pragma unroll
    for (int e = 0; e < 8; ++e) o[e] = f2bf(Wi[(size_t)(kb + e) * A_ + a]);
    *reinterpret_cast<uint4*>(&Bp[((size_t)(n * 64 + ks) * 64 + l) * 8]) =
        *reinterpret_cast<const uint4*>(o);
}

// ---- qe = q @ W + bias ; 2 rows per block, 512 blocks
__global__ void qproj(const float* __restrict__ q, const float* __restrict__ W,
                      const float* __restrict__ bias, float* __restrict__ qe) {
    __shared__ float qs[2][D_];
    int b0 = blockIdx.x * 2;
    int a  = blockIdx.y * 256 + threadIdx.x;
    for (int i = threadIdx.x; i < 2 * D_; i += 256)
        qs[i >> 10][i & 1023] = q[(b0 + (i >> 10)) * D_ + (i & 1023)];
    __syncthreads();
    float a0 = bias[a], a1 = a0;
    #pragma unroll 8
    for (int d = 0; d < D_; ++d) {
        float w = W[d * A_ + a];
        a0 += qs[0][d] * w;
        a1 += qs[1][d] * w;
    }
    qe[b0 * A_ + a] = a0;
    qe[(b0 + 1) * A_ + a] = a1;
}

// ---- fused: scores[row] = Ws . tanh(qe[b] + img[row]@Wi), row = b*S+s
// 128 rows/block, 8 waves (2x4); wave tile 64x128 via 32x32x16 MFMA.
// B fragment-packed in L2 -> VGPR (1-kslice-ahead prefetch); img nt-loaded
// (keeps Bp L2-resident); A double-buffered in LDS, XOR-swizzled.
#define MT 128
#define KT 64

__global__ __launch_bounds__(512, 2)
void score_kernel(const float* __restrict__ img,
                  const unsigned short* __restrict__ Bp,
                  const float* __restrict__ qe,
                  const float* __restrict__ Ws,
                  float* __restrict__ scores)
{
    __shared__ __align__(16) unsigned short Asm[2][MT][KT];   // 32 KB
    __shared__ float ws_s[A_];
    __shared__ float qe_s[2][A_];
    __shared__ float score_s[MT];

    const int tid  = threadIdx.x;
    const int lane = tid & 63;
    const int wave = tid >> 6;                 // 0..7
    const int wm   = wave >> 2;                // 0..1 row half
    const int wn   = wave & 3;                 // 0..3 col slice
    const long row0 = (long)blockIdx.x * MT;
    const int  b0   = (int)(row0 / S_);
    const long b0s  = (long)b0 * S_;

    if (tid < A_) {
        ws_s[tid]    = Ws[tid];
        qe_s[0][tid] = qe[b0 * A_ + tid];
        qe_s[1][tid] = (b0 + 1 < B_) ? qe[(b0 + 1) * A_ + tid] : 0.f;
    }
    if (tid < MT) score_s[tid] = 0.f;

    f32x16 acc[2][4];
    #pragma unroll
    for (int m = 0; m < 2; ++m)
        #pragma unroll
        for (int n = 0; n < 4; ++n) acc[m][n] = (f32x16)0.f;

    const int srow = tid >> 2;                 // 0..127
    const int sseg = (tid & 3) * 2;            // {0,2,4,6}
    const float* gsrc = &img[(size_t)(row0 + srow) * D_ + sseg * 8];

    auto STAGE = [&](int buf, int t) {
        const float* g = gsrc + t * KT;
        f32x4v v0 = __builtin_nontemporal_load(reinterpret_cast<const f32x4v*>(g));
        f32x4v v1 = __builtin_nontemporal_load(reinterpret_cast<const f32x4v*>(g + 4));
        f32x4v v2 = __builtin_nontemporal_load(reinterpret_cast<const f32x4v*>(g + 8));
        f32x4v v3 = __builtin_nontemporal_load(reinterpret_cast<const f32x4v*>(g + 12));
        uint4 u0, u1;
        u0.x = pk2(v0.x, v0.y); u0.y = pk2(v0.z, v0.w);
        u0.z = pk2(v1.x, v1.y); u0.w = pk2(v1.z, v1.w);
        u1.x = pk2(v2.x, v2.y); u1.y = pk2(v2.z, v2.w);
        u1.z = pk2(v3.x, v3.y); u1.w = pk2(v3.z, v3.w);
        *reinterpret_cast<uint4*>(&Asm[buf][srow][((sseg    ) ^ (srow & 7)) * 8]) = u0;
        *reinterpret_cast<uint4*>(&Asm[buf][srow][((sseg + 1) ^ (srow & 7)) * 8]) = u1;
    };

    const bf16x8_t* __restrict__ Bpv = reinterpret_cast<const bf16x8_t*>(Bp);
    auto BF = [&](int n, int kk) {
        return Bpv[((size_t)(wn * 4 + n) * 64 + kk) * 64 + lane];
    };

    bf16x8_t bA[4], bB[4];
    #pragma unroll
    for (int n = 0; n < 4; ++n) bA[n] = BF(n, 0);

    STAGE(0, 0);
    __syncthreads();

    for (int t = 0; t < D_ / KT; ++t) {
        const int cur = t & 1;
        if (t + 1 < D_ / KT) STAGE(cur ^ 1, t + 1);   // prefetch next A-tile
        #pragma unroll
        for (int ks = 0; ks < 4; ++ks) {
            const int kk4 = t * 4 + ks;
            bf16x8_t (&bu)[4] = (ks & 1) ? bB : bA;   // compile-time after unroll
            bf16x8_t (&bp)[4] = (ks & 1) ? bA : bB;
            if (kk4 + 1 < 64) {
                #pragma unroll
                for (int n = 0; n < 4; ++n) bp[n] = BF(n, kk4 + 1);
            }
            bf16x8_t afr[2];
            #pragma unroll
            for (int m = 0; m < 2; ++m) {
                int r = wm * 64 + m * 32 + (lane & 31);
                int slot = (ks * 2 + (lane >> 5)) ^ (r & 7);
                afr[m] = *reinterpret_cast<const bf16x8_t*>(&Asm[cur][r][slot * 8]);
            }
            #pragma unroll
            for (int m = 0; m < 2; ++m)
                #pragma unroll
                for (int n = 0; n < 4; ++n)
                    acc[m][n] = __builtin_amdgcn_mfma_f32_32x32x16_bf16(
                        afr[m], bu[n], acc[m][n], 0, 0, 0);
        }
        __syncthreads();
    }

    // epilogue: Ws-weighted tanh reduction over this wave's 128 cols
    float part[2][16];
    #pragma unroll
    for (int m = 0; m < 2; ++m)
        #pragma unroll
        for (int rg = 0; rg < 16; ++rg) part[m][rg] = 0.f;

    #pragma unroll
    for (int n = 0; n < 4; ++n) {
        int col = wn * 128 + n * 32 + (lane & 31);
        float w  = ws_s[col];
        float q0 = qe_s[0][col], q1 = qe_s[1][col];
        #pragma unroll
        for (int m = 0; m < 2; ++m) {
            #pragma unroll
            for (int rg = 0; rg < 16; ++rg) {
                int rl = wm * 64 + m * 32 + (rg & 3) + ((rg >> 2) << 3) + ((lane >> 5) << 2);
                float qv = ((row0 + rl - b0s) >= S_) ? q1 : q0;
                float x = acc[m][n][rg] + qv;
                float e = __expf(2.f * x);
                part[m][rg] += w * (1.f - 2.f / (e + 1.f));   // w * tanh(x)
            }
        }
    }
    #pragma unroll
    for (int m = 0; m < 2; ++m)
        #pragma unroll
        for (int rg = 0; rg < 16; ++rg) {
            float v = part[m][rg];
            v += __shfl_xor(v, 1);
            v += __shfl_xor(v, 2);
            v += __shfl_xor(v, 4);
            v += __shfl_xor(v, 8);
            v += __shfl_xor(v, 16);
            if ((lane & 31) == 0) {
                int rl = wm * 64 + m * 32 + (rg & 3) + ((rg >> 2) << 3) + ((lane >> 5) << 2);
                atomicAdd(&score_s[rl], v);
            }
        }
    __syncthreads();
    if (tid < MT) scores[row0 + tid] = score_s[tid];
}

// ---- fused softmax(196) + weighted pool + residual, 512 threads/block
__global__ __launch_bounds__(512)
void softpool(const float* __restrict__ sc, const float* __restrict__ img,
              const float* __restrict__ qin, float* __restrict__ uout) {
    __shared__ float ps[S_];
    __shared__ float red1[8], red2[8];
    int b = blockIdx.x, t = threadIdx.x;
    int lane = t & 63, w = t >> 6;
    float v = (t < S_) ? sc[b * S_ + t] : -1e30f;
    float m = v;
    #pragma unroll
    for (int o = 1; o < 64; o <<= 1) m = fmaxf(m, __shfl_xor(m, o));
    if (lane == 0) red1[w] = m;
    __syncthreads();
    m = fmaxf(fmaxf(fmaxf(red1[0], red1[1]), fmaxf(red1[2], red1[3])),
              fmaxf(fmaxf(red1[4], red1[5]), fmaxf(red1[6], red1[7])));
    float e = (t < S_) ? __expf(v - m) : 0.f;
    float s = e;
    #pragma unroll
    for (int o = 1; o < 64; o <<= 1) s += __shfl_xor(s, o);
    if (lane == 0) red2[w] = s;
    __syncthreads();
    s = (red2[0] + red2[1]) + (red2[2] + red2[3]) +
        (red2[4] + red2[5]) + (red2[6] + red2[7]);
    if (t < S_) ps[t] = e / s;
    __syncthreads();

    int d0 = t * 2;
    const float* ib = &img[(size_t)b * S_ * D_ + d0];
    float a0 = 0.f, a1 = 0.f;
    #pragma unroll 4
    for (int sI = 0; sI < S_; ++sI) {
        float2 x = *reinterpret_cast<const float2*>(&ib[(size_t)sI * D_]);
        float p = ps[sI];
        a0 += p * x.x; a1 += p * x.y;
    }
    float2 q = *reinterpret_cast<const float2*>(&qin[(size_t)b * D_ + d0]);
    float2 o2 = make_float2(q.x + a0, q.y + a1);
    *reinterpret_cast<float2*>(&uout[(size_t)b * D_ + d0]) = o2;
}

// ---- out = u @ Wfc + bfc ; 4 rows per block
__global__ void fcout(const float* __restrict__ u, const float* __restrict__ W,
                      const float* __restrict__ bias, float* __restrict__ out) {
    __shared__ float us[4][D_];
    int b0 = blockIdx.x * 4;
    int o  = blockIdx.y * 256 + threadIdx.x;
    for (int i = threadIdx.x; i < 4 * D_; i += 256)
        us[i >> 10][i & 1023] = u[(b0 + (i >> 10)) * D_ + (i & 1023)];
    __syncthreads();
    if (o < O_) {
        float acc[4];
        float bb = bias[o];
        #pragma unroll
        for (int j = 0; j < 4; ++j) acc[j] = bb;
        #pragma unroll 4
        for (int d = 0; d < D_; ++d) {
            float w = W[d * O_ + o];
            #pragma unroll
            for (int j = 0; j < 4; ++j) acc[j] += us[j][d] * w;
        }
        #pragma unroll
        for (int j = 0; j < 4; ++j) out[(b0 + j) * O_ + o] = acc[j];
    }
}

extern "C" void kernel_launch(void* const* d_in, const int* in_sizes, int n_in,
                              void* d_out, int out_size, void* d_ws, size_t ws_size,
                              hipStream_t stream) {
    (void)in_sizes; (void)n_in; (void)out_size; (void)ws_size;
    const float* ques = (const float*)d_in[0];
    const float* img  = (const float*)d_in[1];
    const float* W11  = (const float*)d_in[2];
    const float* b11  = (const float*)d_in[3];
    const float* W12  = (const float*)d_in[4];
    const float* W13  = (const float*)d_in[5];
    // d_in[6] = b13: softmax-invariant, unused
    const float* W21  = (const float*)d_in[7];
    const float* b21  = (const float*)d_in[8];
    const float* W22  = (const float*)d_in[9];
    const float* W23  = (const float*)d_in[10];
    // d_in[11] = b23: softmax-invariant, unused
    const float* Wfc  = (const float*)d_in[12];
    const float* bfc  = (const float*)d_in[13];
    float* out = (float*)d_out;

    char* ws = (char*)d_ws;
    unsigned short* Bp1 = (unsigned short*)ws; ws += (size_t)A_ * D_ * 2;  // 1 MB
    unsigned short* Bp2 = (unsigned short*)ws; ws += (size_t)A_ * D_ * 2;  // 1 MB
    float* qe = (float*)ws; ws += (size_t)B_ * A_ * 4;                     // 1 MB
    float* sc = (float*)ws; ws += (size_t)B_ * S_ * 4;                     // 392 KB
    float* u1 = (float*)ws; ws += (size_t)B_ * D_ * 4;                     // 2 MB
    float* u2 = (float*)ws;                                                // 2 MB

    const int nscore = (B_ * S_) / MT;   // 784

    // hop 1
    bpack<<<dim3(16, 64), 64, 0, stream>>>(W12, Bp1);
    qproj<<<dim3(B_ / 2, A_ / 256), 256, 0, stream>>>(ques, W11, b11, qe);
    score_kernel<<<dim3(nscore), 512, 0, stream>>>(img, Bp1, qe, W13, sc);
    softpool<<<dim3(B_), 512, 0, stream>>>(sc, img, ques, u1);

    // hop 2
    bpack<<<dim3(16, 64), 64, 0, stream>>>(W22, Bp2);
    qproj<<<dim3(B_ / 2, A_ / 256), 256, 0, stream>>>(u1, W21, b21, qe);
    score_kernel<<<dim3(nscore), 512, 0, stream>>>(img, Bp2, qe, W23, sc);
    softpool<<<dim3(B_), 512, 0, stream>>>(sc, img, u1, u2);

    // final FC
    fcout<<<dim3(B_ / 4, (O_ + 255) / 256), 256, 0, stream>>>(u2, Wfc, bfc, out);
}

// Round 5
// 715.944 us; speedup vs baseline: 1.2410x; 1.2410x over previous
//
#include <hip/hip_runtime.h>
#include <hip/hip_bf16.h>

#define B_  512
#define S_  196
#define D_  1024
#define A_  512
#define O_  1000
#define NROW (B_ * S_)   // 100352

typedef __attribute__((ext_vector_type(8))) __bf16 bf16x8_t;
typedef __attribute__((ext_vector_type(16))) float f32x16;
typedef __attribute__((ext_vector_type(4))) float f32x4v;

__device__ __forceinline__ unsigned short f2bf(float f) {
    union { float f; unsigned u; } v; v.f = f;
    unsigned r = v.u + 0x7FFFu + ((v.u >> 16) & 1u);   // RNE
    return (unsigned short)(r >> 16);
}
__device__ __forceinline__ unsigned pk2(float lo, float hi) {
    return (unsigned)f2bf(lo) | ((unsigned)f2bf(hi) << 16);
}
__device__ __forceinline__ float bf2f(unsigned short h) {
    union { unsigned u; float f; } v; v.u = ((unsigned)h) << 16;
    return v.f;
}

// ---- img [NROW][1024] f32 -> imgbf bf16, 16B slots swizzled: slot' = slot ^ (row&7)
__global__ void img2bf(const float* __restrict__ img, unsigned short* __restrict__ imgbf) {
    size_t gid = (size_t)blockIdx.x * 256 + threadIdx.x;
    int row = (int)(gid >> 7);
    int c   = (int)(gid & 127);
    int kb = c >> 3, slot = c & 7;
    const float* src = &img[(size_t)row * D_ + kb * 64 + slot * 8];
    f32x4v v0 = __builtin_nontemporal_load(reinterpret_cast<const f32x4v*>(src));
    f32x4v v1 = __builtin_nontemporal_load(reinterpret_cast<const f32x4v*>(src + 4));
    uint4 u;
    u.x = pk2(v0.x, v0.y); u.y = pk2(v0.z, v0.w);
    u.z = pk2(v1.x, v1.y); u.w = pk2(v1.z, v1.w);
    *reinterpret_cast<uint4*>(
        &imgbf[(size_t)row * D_ + kb * 64 + (slot ^ (row & 7)) * 8]) = u;
}

// ---- pack Wi [D][A] f32 -> Bp fragment-linear bf16: [nfrag(16)][kk(64)][lane(64)][8]
__global__ void bpack(const float* __restrict__ Wi, unsigned short* __restrict__ Bp) {
    int n = blockIdx.x, ks = blockIdx.y, l = threadIdx.x;
    int a  = n * 32 + (l & 31);
    int kb = ks * 16 + (l >> 5) * 8;
    unsigned short o[8];
    #pragma unroll
    for (int e = 0; e < 8; ++e) o[e] = f2bf(Wi[(size_t)(kb + e) * A_ + a]);
    *reinterpret_cast<uint4*>(&Bp[((size_t)(n * 64 + ks) * 64 + l) * 8]) =
        *reinterpret_cast<const uint4*>(o);
}

// ---- qe = q @ W + bias ; 4 rows per block
__global__ void qproj(const float* __restrict__ q, const float* __restrict__ W,
                      const float* __restrict__ bias, float* __restrict__ qe) {
    __shared__ float qs[4][D_];
    int b0 = blockIdx.x * 4;
    int a  = blockIdx.y * 256 + threadIdx.x;
    for (int i = threadIdx.x; i < 4 * D_; i += 256)
        qs[i >> 10][i & 1023] = q[(b0 + (i >> 10)) * D_ + (i & 1023)];
    __syncthreads();
    float acc[4];
    float bb = bias[a];
    #pragma unroll
    for (int j = 0; j < 4; ++j) acc[j] = bb;
    #pragma unroll 8
    for (int d = 0; d < D_; ++d) {
        float w = W[d * A_ + a];
        #pragma unroll
        for (int j = 0; j < 4; ++j) acc[j] += qs[j][d] * w;
    }
    #pragma unroll
    for (int j = 0; j < 4; ++j) qe[(b0 + j) * A_ + a] = acc[j];
}

// ---- fused: scores[row] = Ws . tanh(qe[b] + img[row]@Wi)
// 128 rows/block, 8 waves (2x4); wave tile 64x128 via 32x32x16 MFMA.
// A: bf16 pre-swizzled global -> LDS via global_load_lds (16B), double-buffered,
//    counted vmcnt + raw barrier. B: fragment-packed L2 -> VGPR, 1-ks-ahead prefetch.
#define MT 128
#define KT 64
#define NT (D_ / KT)   // 16

__global__ __launch_bounds__(512, 2)
void score_kernel(const unsigned short* __restrict__ imgbf,
                  const unsigned short* __restrict__ Bp,
                  const float* __restrict__ qe,
                  const float* __restrict__ Ws,
                  float* __restrict__ scores)
{
    __shared__ __align__(16) unsigned short Asm[2][MT][KT];   // 32 KB
    __shared__ float ws_s[A_];
    __shared__ float qe_s[2][A_];
    __shared__ float score_s[MT];

    const int tid  = threadIdx.x;
    const int lane = tid & 63;
    const int wave = tid >> 6;                 // 0..7
    const int wm   = wave >> 2;                // 0..1 row half
    const int wn   = wave & 3;                 // 0..3 col slice
    const long row0 = (long)blockIdx.x * MT;
    const int  b0   = (int)(row0 / S_);
    const long b0s  = (long)b0 * S_;

    if (tid < A_) {
        ws_s[tid]    = Ws[tid];
        qe_s[0][tid] = qe[b0 * A_ + tid];
        qe_s[1][tid] = (b0 + 1 < B_) ? qe[(b0 + 1) * A_ + tid] : 0.f;
    }
    if (tid < MT) score_s[tid] = 0.f;

    f32x16 acc[2][4];
    #pragma unroll
    for (int m = 0; m < 2; ++m)
        #pragma unroll
        for (int n = 0; n < 4; ++n) acc[m][n] = (f32x16)0.f;

    // staging: per wave 2 x global_load_lds(16B); 8 rows (128B) per instruction.
    // imgbf is pre-swizzled so linear LDS dest yields swizzled [row][slot] layout.
    const unsigned short* g0 =
        imgbf + (size_t)(row0 + wave * 16 + (lane >> 3)) * D_ + (lane & 7) * 8;

    auto STAGE = [&](int buf, int t) {
        #pragma unroll
        for (int j = 0; j < 2; ++j) {
            const unsigned short* g = g0 + (size_t)j * 8 * D_ + t * KT;
            __builtin_amdgcn_global_load_lds(
                (const __attribute__((address_space(1))) void*)g,
                (__attribute__((address_space(3))) void*)&Asm[buf][wave * 16 + j * 8][0],
                16, 0, 0);
        }
    };

    const bf16x8_t* __restrict__ Bpv = reinterpret_cast<const bf16x8_t*>(Bp);
    auto BF = [&](int n, int kk) {
        return Bpv[((size_t)(wn * 4 + n) * 64 + kk) * 64 + lane];
    };

    bf16x8_t bA[4], bB[4];
    #pragma unroll
    for (int n = 0; n < 4; ++n) bA[n] = BF(n, 0);

    STAGE(0, 0);
    __syncthreads();

    for (int t = 0; t < NT; ++t) {
        const int cur = t & 1;
        if (t + 1 < NT) STAGE(cur ^ 1, t + 1);       // async prefetch next A-tile
        __builtin_amdgcn_sched_barrier(0);           // pin gload_lds issue first
        #pragma unroll
        for (int ks = 0; ks < 4; ++ks) {
            const int kk4 = t * 4 + ks;
            bf16x8_t (&bu)[4] = (ks & 1) ? bB : bA;
            bf16x8_t (&bp)[4] = (ks & 1) ? bA : bB;
            if (kk4 + 1 < 64) {
                #pragma unroll
                for (int n = 0; n < 4; ++n) bp[n] = BF(n, kk4 + 1);
            }
            bf16x8_t afr[2];
            #pragma unroll
            for (int m = 0; m < 2; ++m) {
                int r = wm * 64 + m * 32 + (lane & 31);
                int slot = (ks * 2 + (lane >> 5)) ^ (r & 7);
                afr[m] = *reinterpret_cast<const bf16x8_t*>(&Asm[cur][r][slot * 8]);
            }
            #pragma unroll
            for (int m = 0; m < 2; ++m)
                #pragma unroll
                for (int n = 0; n < 4; ++n)
                    acc[m][n] = __builtin_amdgcn_mfma_f32_32x32x16_bf16(
                        afr[m], bu[n], acc[m][n], 0, 0, 0);
        }
        // drain only the 2 gload_lds (oldest); keep trailing B prefetch in flight
        asm volatile("s_waitcnt vmcnt(4)" ::: "memory");
        __builtin_amdgcn_s_barrier();
        __builtin_amdgcn_sched_barrier(0);           // no hoists across barrier
    }

    // epilogue: Ws-weighted tanh reduction over this wave's 128 cols
    float part[2][16];
    #pragma unroll
    for (int m = 0; m < 2; ++m)
        #pragma unroll
        for (int rg = 0; rg < 16; ++rg) part[m][rg] = 0.f;

    #pragma unroll
    for (int n = 0; n < 4; ++n) {
        int col = wn * 128 + n * 32 + (lane & 31);
        float w  = ws_s[col];
        float q0 = qe_s[0][col], q1 = qe_s[1][col];
        #pragma unroll
        for (int m = 0; m < 2; ++m) {
            #pragma unroll
            for (int rg = 0; rg < 16; ++rg) {
                int rl = wm * 64 + m * 32 + (rg & 3) + ((rg >> 2) << 3) + ((lane >> 5) << 2);
                float qv = ((row0 + rl - b0s) >= S_) ? q1 : q0;
                float x = acc[m][n][rg] + qv;
                float e = __expf(2.f * x);
                part[m][rg] += w * (1.f - 2.f / (e + 1.f));   // w * tanh(x)
            }
        }
    }
    #pragma unroll
    for (int m = 0; m < 2; ++m)
        #pragma unroll
        for (int rg = 0; rg < 16; ++rg) {
            float v = part[m][rg];
            v += __shfl_xor(v, 1);
            v += __shfl_xor(v, 2);
            v += __shfl_xor(v, 4);
            v += __shfl_xor(v, 8);
            v += __shfl_xor(v, 16);
            if ((lane & 31) == 0) {
                int rl = wm * 64 + m * 32 + (rg & 3) + ((rg >> 2) << 3) + ((lane >> 5) << 2);
                atomicAdd(&score_s[rl], v);
            }
        }
    __syncthreads();
    if (tid < MT) scores[row0 + tid] = score_s[tid];
}

// ---- fused softmax(196) + weighted pool (bf16 img) + residual
__global__ __launch_bounds__(256)
void softpool(const float* __restrict__ sc, const unsigned short* __restrict__ imgbf,
              const float* __restrict__ qin, float* __restrict__ uout) {
    __shared__ float ps[S_];
    __shared__ float red1[4], red2[4];
    int b = blockIdx.x, t = threadIdx.x;
    int lane = t & 63, w = t >> 6;
    float v = (t < S_) ? sc[b * S_ + t] : -1e30f;
    float m = v;
    #pragma unroll
    for (int o = 1; o < 64; o <<= 1) m = fmaxf(m, __shfl_xor(m, o));
    if (lane == 0) red1[w] = m;
    __syncthreads();
    m = fmaxf(fmaxf(red1[0], red1[1]), fmaxf(red1[2], red1[3]));
    float e = (t < S_) ? __expf(v - m) : 0.f;
    float s = e;
    #pragma unroll
    for (int o = 1; o < 64; o <<= 1) s += __shfl_xor(s, o);
    if (lane == 0) red2[w] = s;
    __syncthreads();
    s = (red2[0] + red2[1]) + (red2[2] + red2[3]);
    if (t < S_) ps[t] = e / s;
    __syncthreads();

    // pool: thread covers logical d = c*8 + h*4 + 0..3 ; unswizzle via XOR
    int c = t >> 1, h = t & 1;
    int kb = c >> 3, slot = c & 7;
    const unsigned short* base = imgbf + (size_t)b * S_ * D_ + kb * 64 + h * 4;
    float a0 = 0.f, a1 = 0.f, a2 = 0.f, a3 = 0.f;
    int rr = (b * S_) & 7;
    #pragma unroll 4
    for (int sI = 0; sI < S_; ++sI) {
        const unsigned short* p16 = base + (size_t)sI * D_ + ((slot ^ rr) * 8);
        ushort4 uv = *reinterpret_cast<const ushort4*>(p16);
        float p = ps[sI];
        a0 += p * bf2f(uv.x); a1 += p * bf2f(uv.y);
        a2 += p * bf2f(uv.z); a3 += p * bf2f(uv.w);
        rr = (rr + 1) & 7;
    }
    int d = c * 8 + h * 4;
    float4 q4 = *reinterpret_cast<const float4*>(&qin[(size_t)b * D_ + d]);
    float4 o4 = make_float4(q4.x + a0, q4.y + a1, q4.z + a2, q4.w + a3);
    *reinterpret_cast<float4*>(&uout[(size_t)b * D_ + d]) = o4;
}

// ---- out = u @ Wfc + bfc ; 8 rows per block
__global__ void fcout(const float* __restrict__ u, const float* __restrict__ W,
                      const float* __restrict__ bias, float* __restrict__ out) {
    __shared__ float us[8][D_];
    int b0 = blockIdx.x * 8;
    int o  = blockIdx.y * 256 + threadIdx.x;
    for (int i = threadIdx.x; i < 8 * D_; i += 256)
        us[i >> 10][i & 1023] = u[(b0 + (i >> 10)) * D_ + (i & 1023)];
    __syncthreads();
    if (o < O_) {
        float acc[8];
        float bb = bias[o];
        #pragma unroll
        for (int j = 0; j < 8; ++j) acc[j] = bb;
        #pragma unroll 4
        for (int d = 0; d < D_; ++d) {
            float w = W[d * O_ + o];
            #pragma unroll
            for (int j = 0; j < 8; ++j) acc[j] += us[j][d] * w;
        }
        #pragma unroll
        for (int j = 0; j < 8; ++j) out[(b0 + j) * O_ + o] = acc[j];
    }
}

extern "C" void kernel_launch(void* const* d_in, const int* in_sizes, int n_in,
                              void* d_out, int out_size, void* d_ws, size_t ws_size,
                              hipStream_t stream) {
    (void)in_sizes; (void)n_in; (void)out_size; (void)ws_size;
    const float* ques = (const float*)d_in[0];
    const float* img  = (const float*)d_in[1];
    const float* W11  = (const float*)d_in[2];
    const float* b11  = (const float*)d_in[3];
    const float* W12  = (const float*)d_in[4];
    const float* W13  = (const float*)d_in[5];
    // d_in[6] = b13: softmax-invariant, unused
    const float* W21  = (const float*)d_in[7];
    const float* b21  = (const float*)d_in[8];
    const float* W22  = (const float*)d_in[9];
    const float* W23  = (const float*)d_in[10];
    // d_in[11] = b23: softmax-invariant, unused
    const float* Wfc  = (const float*)d_in[12];
    const float* bfc  = (const float*)d_in[13];
    float* out = (float*)d_out;

    char* ws = (char*)d_ws;
    unsigned short* imgbf = (unsigned short*)ws; ws += (size_t)NROW * D_ * 2;  // 205.5 MB
    unsigned short* Bp1 = (unsigned short*)ws; ws += (size_t)A_ * D_ * 2;      // 1 MB
    unsigned short* Bp2 = (unsigned short*)ws; ws += (size_t)A_ * D_ * 2;      // 1 MB
    float* qe = (float*)ws; ws += (size_t)B_ * A_ * 4;                         // 1 MB
    float* sc = (float*)ws; ws += (size_t)B_ * S_ * 4;                         // 392 KB
    float* u1 = (float*)ws; ws += (size_t)B_ * D_ * 4;                         // 2 MB
    float* u2 = (float*)ws;                                                    // 2 MB

    const int nscore = NROW / MT;   // 784

    img2bf<<<dim3(NROW * 128 / 256), 256, 0, stream>>>(img, imgbf);

    // hop 1
    bpack<<<dim3(16, 64), 64, 0, stream>>>(W12, Bp1);
    qproj<<<dim3(B_ / 4, A_ / 256), 256, 0, stream>>>(ques, W11, b11, qe);
    score_kernel<<<dim3(nscore), 512, 0, stream>>>(imgbf, Bp1, qe, W13, sc);
    softpool<<<dim3(B_), 256, 0, stream>>>(sc, imgbf, ques, u1);

    // hop 2
    bpack<<<dim3(16, 64), 64, 0, stream>>>(W22, Bp2);
    qproj<<<dim3(B_ / 4, A_ / 256), 256, 0, stream>>>(u1, W21, b21, qe);
    score_kernel<<<dim3(nscore), 512, 0, stream>>>(imgbf, Bp2, qe, W23, sc);
    softpool<<<dim3(B_), 256, 0, stream>>>(sc, imgbf, u1, u2);

    // final FC
    fcout<<<dim3(B_ / 8, (O_ + 255) / 256), 256, 0, stream>>>(u2, Wfc, bfc, out);
}